// Round 8
// baseline (148.730 us; speedup 1.0000x reference)
//
#include <hip/hip_runtime.h>

// HEGN loss: L_reg + bidirectional chamfer(x, y).  B=8, N=M=4096.
// Single chamfer kernel + tiny memset.  Partial blocks atomicMax an
// order-inverted uint encoding of their per-point chunk-min into mins[zb][p]
// (init = 0 via memset); per-zb finisher blocks (last of 64, via counter)
// decode+sum 4096 mins -> zbsum[zb]; the last finisher adds L_reg and does a
// single plain store to out.  Reduce overlaps the partial tail; no second
// kernel, no inter-kernel drain, 8 MB partial traffic -> 0.5 MB.
#define BB 8
#define NN 4096
#define MC 256                    // reference points staged per chunk
#define NCHUNK (NN / MC)          // 16
#define KPT 4                     // query points per thread -> 1024 blocks
#define TPB 256
#define PTS_PER_BLOCK (TPB * KPT) // 1024
#define NZB (2 * BB)              // 16 (dir,b) pairs
#define NPTS (NZB * NN)           // 65536

// ws: mins[NPTS] u32 | counter[16] u32 | counter2 u32 | zbsum[16] f32
#define WS_ZERO_WORDS (NPTS + NZB + 1)

// Order-preserving float -> uint, inverted so min(v) == max(code), init 0.
__device__ __forceinline__ unsigned enc_min(float v) {
  const unsigned u = __float_as_uint(v);
  const unsigned key = (u & 0x80000000u) ? ~u : (u | 0x80000000u);
  return ~key;                    // ascending key -> descending code
}
__device__ __forceinline__ float dec_max(unsigned s) {
  const unsigned key = ~s;
  const unsigned u = (key & 0x80000000u) ? (key ^ 0x80000000u) : ~key;
  return __uint_as_float(u);
}

__global__ __launch_bounds__(TPB) void hegn_chamfer(
    const float* __restrict__ X, const float* __restrict__ Y,
    const float* __restrict__ R, const float* __restrict__ S,
    const float* __restrict__ t, const float* __restrict__ Rgt,
    const float* __restrict__ Sgt, const float* __restrict__ tgt,
    unsigned* __restrict__ mins, unsigned* __restrict__ counters,
    unsigned* __restrict__ counter2, float* __restrict__ zbsum,
    float* __restrict__ out) {
  __shared__ float4 ly[MC];       // (-2*y0, -2*y1, -2*y2, |y|^2)
  const int tid = threadIdx.x;
  const int zb  = blockIdx.z;     // (dir<<3) | b
  const int b   = zb & (BB - 1);
  const int dir = zb >> 3;
  const float* pts  = dir ? (Y + b * NN * 3) : (X + b * NN * 3);
  const float* refs = dir ? (X + b * NN * 3) : (Y + b * NN * 3);
  const int c = blockIdx.y;

  {
    const int j = c * MC + tid;   // MC == TPB: one staging iteration
    const float a0 = refs[j * 3 + 0];
    const float a1 = refs[j * 3 + 1];
    const float a2 = refs[j * 3 + 2];
    ly[tid] = make_float4(-2.0f * a0, -2.0f * a1, -2.0f * a2,
                          a0 * a0 + a1 * a1 + a2 * a2);
  }
  __syncthreads();

  float px[KPT], py[KPT], pz[KPT], m[KPT];
  const int p0 = blockIdx.x * PTS_PER_BLOCK + tid;
#pragma unroll
  for (int k = 0; k < KPT; k++) {
    const int p = p0 + k * TPB;
    px[k] = pts[p * 3 + 0];
    py[k] = pts[p * 3 + 1];
    pz[k] = pts[p * 3 + 2];
    m[k] = 1e30f;
  }

  // min over chunk of (|y|^2 - 2 x.y); |x|^2 added after the loop.
#define CHAMFER_BODY(w0, w1, w2, w3)                                           \
  _Pragma("unroll") for (int k = 0; k < KPT; k++) {                            \
    const float s0 =                                                           \
        fmaf(px[k], w0.x, fmaf(py[k], w0.y, fmaf(pz[k], w0.z, w0.w)));         \
    const float s1 =                                                           \
        fmaf(px[k], w1.x, fmaf(py[k], w1.y, fmaf(pz[k], w1.z, w1.w)));         \
    const float s2 =                                                           \
        fmaf(px[k], w2.x, fmaf(py[k], w2.y, fmaf(pz[k], w2.z, w2.w)));         \
    const float s3 =                                                           \
        fmaf(px[k], w3.x, fmaf(py[k], w3.y, fmaf(pz[k], w3.z, w3.w)));         \
    m[k] = fminf(m[k], fminf(fminf(s0, s1), fminf(s2, s3)));                   \
  }

  float4 w0 = ly[0], w1 = ly[1], w2 = ly[2], w3 = ly[3];
#pragma unroll 2
  for (int j = 0; j < MC - 4; j += 4) {
    const float4 n0 = ly[j + 4];
    const float4 n1 = ly[j + 5];
    const float4 n2 = ly[j + 6];
    const float4 n3 = ly[j + 7];
    CHAMFER_BODY(w0, w1, w2, w3)
    w0 = n0; w1 = n1; w2 = n2; w3 = n3;
  }
  CHAMFER_BODY(w0, w1, w2, w3)
#undef CHAMFER_BODY

#pragma unroll
  for (int k = 0; k < KPT; k++) {
    const int p = p0 + k * TPB;
    const float pn = px[k] * px[k] + py[k] * py[k] + pz[k] * pz[k];
    atomicMax(&mins[zb * NN + p], enc_min(m[k] + pn));
  }

  // ---- per-zb completion count; last of 64 blocks becomes zb-finisher ----
  __threadfence();
  __shared__ unsigned is_fin;
  if (tid == 0) is_fin = (atomicAdd(&counters[zb], 1u) == 63u) ? 1u : 0u;
  __syncthreads();
  if (!is_fin) return;

  __threadfence();                // acquire: all zb blocks' maxes visible
  const uint4* mz = (const uint4*)(mins + zb * NN);
  float s = 0.0f;
#pragma unroll
  for (int i = 0; i < 4; i++) {   // 4096 mins, 16 per thread
    const uint4 v = mz[i * TPB + tid];
    s += (dec_max(v.x) + dec_max(v.y)) + (dec_max(v.z) + dec_max(v.w));
  }
  for (int o = 32; o > 0; o >>= 1) s += __shfl_down(s, o);
  __shared__ float wsum[4];
  if ((tid & 63) == 0) wsum[tid >> 6] = s;
  __syncthreads();
  __shared__ unsigned is_last;
  if (tid == 0) {
    zbsum[zb] = wsum[0] + wsum[1] + wsum[2] + wsum[3];
    __threadfence();
    is_last = (atomicAdd(counter2, 1u) == (unsigned)(NZB - 1)) ? 1u : 0u;
  }
  __syncthreads();
  if (!is_last) return;

  // ---- final: sum 16 zbsums + L_reg, single plain store to out ----
  __threadfence();
  float v = 0.0f;
  if (tid < 72) {                       // R @ R_gt^T - I, squared
    const int bb = tid / 9, ik = tid % 9, i = ik / 3, k = ik % 3;
    const float* Rb = R + bb * 9;
    const float* Gb = Rgt + bb * 9;
    float d = Rb[i * 3 + 0] * Gb[k * 3 + 0] +
              Rb[i * 3 + 1] * Gb[k * 3 + 1] +
              Rb[i * 3 + 2] * Gb[k * 3 + 2];
    d -= (i == k) ? 1.0f : 0.0f;
    v = d * d;
  } else if (tid < 96) {                // (S - S_gt)^2
    const int i = tid - 72;
    const float d = S[i] - Sgt[i];
    v = d * d;
  } else if (tid < 120) {               // (t - t_gt)^2
    const int i = tid - 96;
    const float d = t[i] - tgt[i];
    v = d * d;
  }
  if (tid < NZB) v += zbsum[tid] * (1.0f / (float)(BB * NN));
  for (int o = 32; o > 0; o >>= 1) v += __shfl_down(v, o);
  __shared__ float rsum[4];
  if ((tid & 63) == 0) rsum[tid >> 6] = v;
  __syncthreads();
  if (tid == 0) *out = rsum[0] + rsum[1] + rsum[2] + rsum[3];
}

extern "C" void kernel_launch(void* const* d_in, const int* in_sizes, int n_in,
                              void* d_out, int out_size, void* d_ws, size_t ws_size,
                              hipStream_t stream) {
  const float* X   = (const float*)d_in[0];
  const float* Y   = (const float*)d_in[1];
  const float* R   = (const float*)d_in[2];
  const float* S   = (const float*)d_in[3];
  const float* t   = (const float*)d_in[4];
  const float* Rgt = (const float*)d_in[5];
  const float* Sgt = (const float*)d_in[6];
  const float* tgt = (const float*)d_in[7];

  unsigned* mins     = (unsigned*)d_ws;
  unsigned* counters = mins + NPTS;
  unsigned* counter2 = counters + NZB;
  float*    zbsum    = (float*)(counter2 + 1);
  float*    out      = (float*)d_out;

  // mins + counters + counter2 must start at 0 (code 0 == +inf min).
  hipMemsetAsync(d_ws, 0, WS_ZERO_WORDS * sizeof(unsigned), stream);

  dim3 gA(NN / PTS_PER_BLOCK, NCHUNK, NZB);   // (4, 16, 16) = 1024 blocks
  hegn_chamfer<<<gA, TPB, 0, stream>>>(X, Y, R, S, t, Rgt, Sgt, tgt,
                                       mins, counters, counter2, zbsum, out);
}

// Round 9
// 102.590 us; speedup vs baseline: 1.4498x; 1.4498x over previous
//
#include <hip/hip_runtime.h>

// HEGN loss: L_reg + bidirectional chamfer(x, y).  B=8, N=M=4096.
// MFMA chamfer: d2 = |r|^2 - 2 q.r (+|q|^2 after min), computed fp32-faithfully
// via 3-way bf16 splits packed into K=32 of mfma_f32_16x16x32_bf16.
//   prep:    pack refs -> A-fragments (LDS-chunk layout), queries -> B-frags,
//            |q|^2 array.  Also zeroes out.
//   chamfer: per block (zb, chunk c, 512 queries): 4 waves x 8 B-frags(regs),
//            A-chunk in LDS; 16 tiles x {1 ds_read_b128 + 8 MFMA + 32 fmin}.
//            VALU cost: 1 lane-op/pair (min) vs 4 for the FMA version.
//   reduce:  R7's verified float4 cross-chunk min + sum + L_reg.
#define BB 8
#define NN 4096
#define NZB 16                    // (dir,b) pairs
#define MC 256                    // refs per chunk
#define NCHUNK (NN / MC)          // 16
#define TPB 256
#define NPTS (NZB * NN)           // 65536

typedef short short8 __attribute__((ext_vector_type(8)));
typedef float f32x4 __attribute__((ext_vector_type(4)));

// ws layout (shorts/floats):
//   Apack: [NZB][NCHUNK][8192 shorts]   (4 MB)  A-frag chunk images
//   Bpack: [NZB][NN][32 shorts]         (4 MB)  B-frag rows
//   qn:    [NZB][NN] float              (256 KB)
//   partial: [NCHUNK][NZB][NN] float    (4 MB)
#define APACK_SHORTS (NZB * NCHUNK * 8192)
#define BPACK_SHORTS (NZB * NN * 32)

__device__ __forceinline__ unsigned short b16(float v) {
  const unsigned u = __float_as_uint(v);
  return (unsigned short)((u + 0x7fffu + ((u >> 16) & 1u)) >> 16);
}
__device__ __forceinline__ float fb16(unsigned short h) {
  return __uint_as_float(((unsigned)h) << 16);
}
__device__ __forceinline__ void split3(float v, unsigned short* o) {
  const unsigned short h0 = b16(v); const float f0 = fb16(h0);
  const unsigned short h1 = b16(v - f0); const float f1 = fb16(h1);
  const unsigned short h2 = b16(v - f0 - f1);
  o[0] = h0; o[1] = h1; o[2] = h2;
}

// K-slot pairing per dim-block d (k = 8d+j):  A: r0 r0 r1 r1 r0 r2 r1 r2
//                                             B: s0 s1 s0 s1 s2 s0 s2 s1
// -> all split products except (r2,s2): error ~2^-32 relative.
// k-block 3: A: n0 n1 n2 0...  B: 1 1 1 0...  adds |r|^2 exactly.
__global__ __launch_bounds__(TPB) void hegn_prep(
    const float* __restrict__ X, const float* __restrict__ Y,
    unsigned short* __restrict__ Apack, unsigned short* __restrict__ Bpack,
    float* __restrict__ qn, float* __restrict__ out) {
  const int id = blockIdx.x * TPB + threadIdx.x;   // 2*NZB*NN ids
  if (id == 0) *out = 0.0f;                        // zero for reduce atomics
  const int role = id >> 16;        // 0 = A(refs), 1 = B(queries)
  const int zb = (id >> 12) & 15;
  const int j = id & (NN - 1);
  const int b = zb & 7;
  const int dir = zb >> 3;
  const float* src = (role == 0) ? (dir ? X + b * NN * 3 : Y + b * NN * 3)
                                 : (dir ? Y + b * NN * 3 : X + b * NN * 3);
  const float a0 = src[j * 3 + 0];
  const float a1 = src[j * 3 + 1];
  const float a2 = src[j * 3 + 2];
  unsigned short s0[3], s1[3], s2[3];
  if (role == 0) {
    split3(a0, s0); split3(a1, s1); split3(a2, s2);
    const float n = fmaf(a0, a0, fmaf(a1, a1, a2 * a2));
    unsigned short n3[3]; split3(n, n3);
    // dest: chunk c=j>>8, tile tt=(j>>4)&15, row=j&15, k-block kb:
    // short offset within chunk = (tt*64 + kb*16 + row)*8
    unsigned short* dst = Apack + (zb * NCHUNK + (j >> 8)) * 8192 +
                          (((j >> 4) & 15) * 64 + (j & 15)) * 8;
    const unsigned short* r[3] = {s0, s1, s2};
#pragma unroll
    for (int d = 0; d < 3; d++) {
      short8 w;
      w[0] = r[d][0]; w[1] = r[d][0]; w[2] = r[d][1]; w[3] = r[d][1];
      w[4] = r[d][0]; w[5] = r[d][2]; w[6] = r[d][1]; w[7] = r[d][2];
      *(short8*)(dst + d * 128) = w;
    }
    short8 w;
    w[0] = n3[0]; w[1] = n3[1]; w[2] = n3[2];
    w[3] = 0; w[4] = 0; w[5] = 0; w[6] = 0; w[7] = 0;
    *(short8*)(dst + 3 * 128) = w;
  } else {
    split3(-2.0f * a0, s0); split3(-2.0f * a1, s1); split3(-2.0f * a2, s2);
    unsigned short* dst = Bpack + (zb * NN + j) * 32;
    const unsigned short* s[3] = {s0, s1, s2};
#pragma unroll
    for (int d = 0; d < 3; d++) {
      short8 w;
      w[0] = s[d][0]; w[1] = s[d][1]; w[2] = s[d][0]; w[3] = s[d][1];
      w[4] = s[d][2]; w[5] = s[d][0]; w[6] = s[d][2]; w[7] = s[d][1];
      *(short8*)(dst + d * 8) = w;
    }
    short8 w;
    w[0] = (short)0x3f80; w[1] = (short)0x3f80; w[2] = (short)0x3f80;
    w[3] = 0; w[4] = 0; w[5] = 0; w[6] = 0; w[7] = 0;
    *(short8*)(dst + 24) = w;
    qn[zb * NN + j] = fmaf(a0, a0, fmaf(a1, a1, a2 * a2));
  }
}

// grid (8, NCHUNK, NZB) = 2048 blocks; block = 4 waves x 128 queries.
__global__ __launch_bounds__(TPB) void hegn_chamfer(
    const unsigned short* __restrict__ Apack,
    const unsigned short* __restrict__ Bpack,
    const float* __restrict__ qn, float* __restrict__ partial) {
  __shared__ short8 As[1024];      // 16 tiles x 64 lanes x 16B = 16 KB
  const int tid = threadIdx.x;
  const int zb = blockIdx.z;
  const int c  = blockIdx.y;
  const int l  = tid & 63;
  const int wid = tid >> 6;
  const int wavebase = blockIdx.x * 512 + wid * 128;

  // Stage A chunk (16 KB, coalesced float4 copy).
  {
    const float4* src = (const float4*)(Apack + (zb * NCHUNK + c) * 8192);
    float4* dst = (float4*)As;
#pragma unroll
    for (int i = 0; i < 4; i++) dst[i * TPB + tid] = src[i * TPB + tid];
  }

  // B-frags (8 x 16 queries) + per-col |q|^2, in registers.
  const int col = l & 15, kb = l >> 4;
  short8 Bf[8]; float qf[8];
#pragma unroll
  for (int f = 0; f < 8; f++) {
    const int q = wavebase + f * 16 + col;
    Bf[f] = *(const short8*)(Bpack + (zb * NN + q) * 32 + kb * 8);
    qf[f] = qn[zb * NN + q];
  }
  float m[8];
#pragma unroll
  for (int f = 0; f < 8; f++) m[f] = 1e30f;
  const f32x4 Z = {0.0f, 0.0f, 0.0f, 0.0f};
  __syncthreads();

#pragma unroll 2
  for (int tt = 0; tt < 16; tt++) {
    const short8 A = As[tt * 64 + l];    // lane l: row=l&15, k=(l>>4)*8+j
#pragma unroll
    for (int f = 0; f < 8; f++) {
      const f32x4 D = __builtin_amdgcn_mfma_f32_16x16x32_bf16(A, Bf[f], Z, 0, 0, 0);
      m[f] = fminf(m[f], fminf(fminf(D[0], D[1]), fminf(D[2], D[3])));
    }
  }

  // Cross-lane: groups l>>4 hold disjoint row-quarters of the same col.
#pragma unroll
  for (int f = 0; f < 8; f++) {
    float v = m[f];
    v = fminf(v, __shfl_xor(v, 16));
    v = fminf(v, __shfl_xor(v, 32));
    m[f] = v + qf[f];
  }
  // lane l -> query wavebase+l (frag l>>4) and wavebase+64+l (frag 4+(l>>4)).
  const int g = l >> 4;
  const float v1 = g == 0 ? m[0] : g == 1 ? m[1] : g == 2 ? m[2] : m[3];
  const float v2 = g == 0 ? m[4] : g == 1 ? m[5] : g == 2 ? m[6] : m[7];
  float* pp = partial + (c * NZB + zb) * NN + wavebase;
  pp[l] = v1;
  pp[64 + l] = v2;
}

// R7's verified reduce: float4 cross-chunk min, block-sum, atomic; + L_reg.
__global__ __launch_bounds__(256) void chamfer_reduce(
    const float4* __restrict__ partial4,
    const float* __restrict__ R, const float* __restrict__ S,
    const float* __restrict__ t, const float* __restrict__ Rgt,
    const float* __restrict__ Sgt, const float* __restrict__ tgt,
    float* __restrict__ out) {
  const int tid = threadIdx.x;
  const int q4 = blockIdx.x * 256 + tid;  // 64 blocks cover NPTS/4
  float4 mn = make_float4(1e30f, 1e30f, 1e30f, 1e30f);
#pragma unroll
  for (int c = 0; c < NCHUNK; c++) {
    const float4 v = partial4[c * (NPTS / 4) + q4];
    mn.x = fminf(mn.x, v.x);
    mn.y = fminf(mn.y, v.y);
    mn.z = fminf(mn.z, v.z);
    mn.w = fminf(mn.w, v.w);
  }
  float s = (mn.x + mn.y) + (mn.z + mn.w);
  for (int o = 32; o > 0; o >>= 1) s += __shfl_down(s, o);
  __shared__ float wsum[4];
  if ((tid & 63) == 0) wsum[tid >> 6] = s;
  __syncthreads();
  if (tid == 0) {
    const float bs = wsum[0] + wsum[1] + wsum[2] + wsum[3];
    atomicAdd(out, bs * (1.0f / (float)(BB * NN)));
  }

  if (blockIdx.x == 0) {
    float v = 0.0f;
    if (tid < 72) {                       // R @ R_gt^T - I, squared
      const int b = tid / 9, ik = tid % 9, i = ik / 3, k = ik % 3;
      const float* Rb = R + b * 9;
      const float* Gb = Rgt + b * 9;
      float d = Rb[i * 3 + 0] * Gb[k * 3 + 0] +
                Rb[i * 3 + 1] * Gb[k * 3 + 1] +
                Rb[i * 3 + 2] * Gb[k * 3 + 2];
      d -= (i == k) ? 1.0f : 0.0f;
      v = d * d;
    } else if (tid < 96) {                // (S - S_gt)^2
      const int i = tid - 72;
      const float d = S[i] - Sgt[i];
      v = d * d;
    } else if (tid < 120) {               // (t - t_gt)^2
      const int i = tid - 96;
      const float d = t[i] - tgt[i];
      v = d * d;
    }
    for (int o = 32; o > 0; o >>= 1) v += __shfl_down(v, o);
    __shared__ float rsum[4];
    if ((tid & 63) == 0) rsum[tid >> 6] = v;
    __syncthreads();
    if (tid == 0) atomicAdd(out, rsum[0] + rsum[1] + rsum[2] + rsum[3]);
  }
}

extern "C" void kernel_launch(void* const* d_in, const int* in_sizes, int n_in,
                              void* d_out, int out_size, void* d_ws, size_t ws_size,
                              hipStream_t stream) {
  const float* X   = (const float*)d_in[0];
  const float* Y   = (const float*)d_in[1];
  const float* R   = (const float*)d_in[2];
  const float* S   = (const float*)d_in[3];
  const float* t   = (const float*)d_in[4];
  const float* Rgt = (const float*)d_in[5];
  const float* Sgt = (const float*)d_in[6];
  const float* tgt = (const float*)d_in[7];

  unsigned short* Apack = (unsigned short*)d_ws;
  unsigned short* Bpack = Apack + APACK_SHORTS;
  float* qn       = (float*)(Bpack + BPACK_SHORTS);
  float* partial  = qn + NPTS;
  float* out      = (float*)d_out;

  hegn_prep<<<2 * NZB * NN / TPB, TPB, 0, stream>>>(X, Y, Apack, Bpack, qn, out);

  dim3 gC(8, NCHUNK, NZB);        // 2048 blocks x 4 waves
  hegn_chamfer<<<gC, TPB, 0, stream>>>(Apack, Bpack, qn, partial);

  chamfer_reduce<<<NPTS / 4 / 256, 256, 0, stream>>>(
      (const float4*)partial, R, S, t, Rgt, Sgt, tgt, out);
}

// Round 10
// 97.617 us; speedup vs baseline: 1.5236x; 1.0509x over previous
//
#include <hip/hip_runtime.h>

// HEGN loss: L_reg + bidirectional chamfer(x, y).  B=8, N=M=4096.
// MFMA chamfer (R9 math, verified absmax=0.0) with in-kernel packing:
//   d2 = |r|^2 - 2 q.r (+|q|^2 after min), fp32-faithful via 3-way bf16
//   splits packed into K=32 of one mfma_f32_16x16x32_bf16 per 16x16 tile.
// No prep kernel, no pack arrays: each block packs its A-chunk from raw
// floats into the LDS fragment image (4 ds_write_b128/thread) and each lane
// packs its 8 B-frags in registers (~40 VALU/point -- far cheaper than the
// 16 MB pack-array round trip that made R9 lose).
// Each block covers CPG=4 chunks with a running register min -> partial is
// 1 MB, reduce does a 4-way min.  Two dispatches total.
#define BB 8
#define NN 4096
#define NZB 16                    // (dir,b) pairs
#define MC 256                    // refs per chunk
#define CPG 4                     // chunks per block
#define NCGRP 4                   // chunk groups = (NN/MC)/CPG
#define TPB 256
#define NPTS (NZB * NN)           // 65536

typedef short short8 __attribute__((ext_vector_type(8)));
typedef float f32x4 __attribute__((ext_vector_type(4)));

__device__ __forceinline__ unsigned short b16(float v) {
  const unsigned u = __float_as_uint(v);
  return (unsigned short)((u + 0x7fffu + ((u >> 16) & 1u)) >> 16);
}
__device__ __forceinline__ float fb16(unsigned short h) {
  return __uint_as_float(((unsigned)h) << 16);
}
__device__ __forceinline__ void split3(float v, unsigned short* o) {
  const unsigned short h0 = b16(v); const float f0 = fb16(h0);
  const unsigned short h1 = b16(v - f0); const float f1 = fb16(h1);
  const unsigned short h2 = b16(v - f0 - f1);
  o[0] = h0; o[1] = h1; o[2] = h2;
}

// K-slot pairing per dim-block d (k = 8d+j):  A: r0 r0 r1 r1 r0 r2 r1 r2
//                                             B: s0 s1 s0 s1 s2 s0 s2 s1
// -> all split products except (r2,s2).  k-block 3: A = (n0,n1,n2,0..),
// B = (1,1,1,0..) adds |r|^2.

// grid (8, NCGRP, NZB) = 512 blocks x 4 waves; each wave owns 128 queries.
__global__ __launch_bounds__(TPB) void hegn_chamfer(
    const float* __restrict__ X, const float* __restrict__ Y,
    float* __restrict__ partial, float* __restrict__ out) {
  __shared__ short8 As[1024];      // 16 tiles x 64 lanes x 16B = 16 KB
  const int tid = threadIdx.x;
  const int zb  = blockIdx.z;
  const int cg  = blockIdx.y;
  const int b   = zb & (BB - 1);
  const int dir = zb >> 3;
  const float* qsrc = dir ? (Y + b * NN * 3) : (X + b * NN * 3);
  const float* rsrc = dir ? (X + b * NN * 3) : (Y + b * NN * 3);
  const int l   = tid & 63;
  const int wid = tid >> 6;
  const int wavebase = blockIdx.x * 512 + wid * 128;

  // Replaces the 4-byte memset dispatch (reduce's atomics need out==0).
  if (tid == 0 && blockIdx.x == 0 && blockIdx.y == 0 && blockIdx.z == 0)
    *out = 0.0f;

  // ---- pack B-frags in registers (once per block) ----
  const int col = l & 15, kb = l >> 4;
  short8 Bf[8]; float qf[8]; float m[8];
#pragma unroll
  for (int f = 0; f < 8; f++) {
    const int q = wavebase + f * 16 + col;
    const float a0 = qsrc[q * 3 + 0];
    const float a1 = qsrc[q * 3 + 1];
    const float a2 = qsrc[q * 3 + 2];
    qf[f] = fmaf(a0, a0, fmaf(a1, a1, a2 * a2));
    short8 w;
    if (kb < 3) {
      const float ad = (kb == 0) ? a0 : (kb == 1) ? a1 : a2;
      unsigned short s[3]; split3(-2.0f * ad, s);
      w[0] = s[0]; w[1] = s[1]; w[2] = s[0]; w[3] = s[1];
      w[4] = s[2]; w[5] = s[0]; w[6] = s[2]; w[7] = s[1];
    } else {
      w[0] = (short)0x3f80; w[1] = (short)0x3f80; w[2] = (short)0x3f80;
      w[3] = 0; w[4] = 0; w[5] = 0; w[6] = 0; w[7] = 0;
    }
    Bf[f] = w;
    m[f] = 1e30f;
  }

  const f32x4 Z = {0.0f, 0.0f, 0.0f, 0.0f};

#pragma unroll 1
  for (int i = 0; i < CPG; i++) {
    const int cbase = (cg * CPG + i) * MC;
    __syncthreads();               // previous iteration's As reads done
    {
      // ---- pack A-chunk into LDS fragment image ----
      const int j = cbase + tid;   // one ref per thread
      const float a0 = rsrc[j * 3 + 0];
      const float a1 = rsrc[j * 3 + 1];
      const float a2 = rsrc[j * 3 + 2];
      unsigned short s0[3], s1[3], s2[3], n3[3];
      split3(a0, s0); split3(a1, s1); split3(a2, s2);
      const float n = fmaf(a0, a0, fmaf(a1, a1, a2 * a2));
      split3(n, n3);
      const int tt = tid >> 4, row = tid & 15;
      short8* dst = &As[tt * 64 + row];        // + kb*16 per k-block
      const unsigned short* r[3] = {s0, s1, s2};
#pragma unroll
      for (int d = 0; d < 3; d++) {
        short8 w;
        w[0] = r[d][0]; w[1] = r[d][0]; w[2] = r[d][1]; w[3] = r[d][1];
        w[4] = r[d][0]; w[5] = r[d][2]; w[6] = r[d][1]; w[7] = r[d][2];
        dst[d * 16] = w;
      }
      short8 w;
      w[0] = n3[0]; w[1] = n3[1]; w[2] = n3[2];
      w[3] = 0; w[4] = 0; w[5] = 0; w[6] = 0; w[7] = 0;
      dst[3 * 16] = w;
    }
    __syncthreads();

    // ---- 16 tiles x 8 frags: 1 LDS read + 8 MFMA + 8 fmin-trees ----
#pragma unroll 2
    for (int tt = 0; tt < 16; tt++) {
      const short8 A = As[tt * 64 + l];  // lane l: row=l&15, k=(l>>4)*8+j
#pragma unroll
      for (int f = 0; f < 8; f++) {
        const f32x4 D =
            __builtin_amdgcn_mfma_f32_16x16x32_bf16(A, Bf[f], Z, 0, 0, 0);
        m[f] = fminf(m[f], fminf(fminf(D[0], D[1]), fminf(D[2], D[3])));
      }
    }
  }

  // Cross-lane: groups l>>4 hold disjoint row-quarters of the same col.
#pragma unroll
  for (int f = 0; f < 8; f++) {
    float v = m[f];
    v = fminf(v, __shfl_xor(v, 16));
    v = fminf(v, __shfl_xor(v, 32));
    m[f] = v + qf[f];
  }
  // lane l -> query wavebase+l (frag l>>4) and wavebase+64+l (frag 4+(l>>4)).
  const int g = l >> 4;
  const float v1 = g == 0 ? m[0] : g == 1 ? m[1] : g == 2 ? m[2] : m[3];
  const float v2 = g == 0 ? m[4] : g == 1 ? m[5] : g == 2 ? m[6] : m[7];
  float* pp = partial + (cg * NZB + zb) * NN + wavebase;
  pp[l] = v1;
  pp[64 + l] = v2;
}

// Verified reduce (R7/R9): float4 cross-group min, block-sum, atomic; + L_reg.
__global__ __launch_bounds__(256) void chamfer_reduce(
    const float4* __restrict__ partial4,
    const float* __restrict__ R, const float* __restrict__ S,
    const float* __restrict__ t, const float* __restrict__ Rgt,
    const float* __restrict__ Sgt, const float* __restrict__ tgt,
    float* __restrict__ out) {
  const int tid = threadIdx.x;
  const int q4 = blockIdx.x * 256 + tid;  // 64 blocks cover NPTS/4
  float4 mn = make_float4(1e30f, 1e30f, 1e30f, 1e30f);
#pragma unroll
  for (int c = 0; c < NCGRP; c++) {
    const float4 v = partial4[c * (NPTS / 4) + q4];
    mn.x = fminf(mn.x, v.x);
    mn.y = fminf(mn.y, v.y);
    mn.z = fminf(mn.z, v.z);
    mn.w = fminf(mn.w, v.w);
  }
  float s = (mn.x + mn.y) + (mn.z + mn.w);
  for (int o = 32; o > 0; o >>= 1) s += __shfl_down(s, o);
  __shared__ float wsum[4];
  if ((tid & 63) == 0) wsum[tid >> 6] = s;
  __syncthreads();
  if (tid == 0) {
    const float bs = wsum[0] + wsum[1] + wsum[2] + wsum[3];
    atomicAdd(out, bs * (1.0f / (float)(BB * NN)));
  }

  if (blockIdx.x == 0) {
    float v = 0.0f;
    if (tid < 72) {                       // R @ R_gt^T - I, squared
      const int b = tid / 9, ik = tid % 9, i = ik / 3, k = ik % 3;
      const float* Rb = R + b * 9;
      const float* Gb = Rgt + b * 9;
      float d = Rb[i * 3 + 0] * Gb[k * 3 + 0] +
                Rb[i * 3 + 1] * Gb[k * 3 + 1] +
                Rb[i * 3 + 2] * Gb[k * 3 + 2];
      d -= (i == k) ? 1.0f : 0.0f;
      v = d * d;
    } else if (tid < 96) {                // (S - S_gt)^2
      const int i = tid - 72;
      const float d = S[i] - Sgt[i];
      v = d * d;
    } else if (tid < 120) {               // (t - t_gt)^2
      const int i = tid - 96;
      const float d = t[i] - tgt[i];
      v = d * d;
    }
    for (int o = 32; o > 0; o >>= 1) v += __shfl_down(v, o);
    __shared__ float rsum[4];
    if ((tid & 63) == 0) rsum[tid >> 6] = v;
    __syncthreads();
    if (tid == 0) atomicAdd(out, rsum[0] + rsum[1] + rsum[2] + rsum[3]);
  }
}

extern "C" void kernel_launch(void* const* d_in, const int* in_sizes, int n_in,
                              void* d_out, int out_size, void* d_ws, size_t ws_size,
                              hipStream_t stream) {
  const float* X   = (const float*)d_in[0];
  const float* Y   = (const float*)d_in[1];
  const float* R   = (const float*)d_in[2];
  const float* S   = (const float*)d_in[3];
  const float* t   = (const float*)d_in[4];
  const float* Rgt = (const float*)d_in[5];
  const float* Sgt = (const float*)d_in[6];
  const float* tgt = (const float*)d_in[7];

  float* partial = (float*)d_ws;         // NCGRP * NPTS floats = 1 MB
  float* out     = (float*)d_out;

  dim3 gC(8, NCGRP, NZB);                // (8, 4, 16) = 512 blocks
  hegn_chamfer<<<gC, TPB, 0, stream>>>(X, Y, partial, out);

  chamfer_reduce<<<NPTS / 4 / 256, 256, 0, stream>>>(
      (const float4*)partial, R, S, t, Rgt, Sgt, tgt, out);
}

// Round 11
// 91.945 us; speedup vs baseline: 1.6176x; 1.0617x over previous
//
#include <hip/hip_runtime.h>

// HEGN loss: L_reg + bidirectional chamfer(x, y).  B=8, N=M=4096.
// Best-measured artifact (R7, 90.17us).  11-experiment history:
//   R7 (this) 90.2 < R1 91.5 < R2 93.4 < R0 94.6 < R5 94.2* < R6 95.8
//   < R4 96.6 < R10 MFMA 97.6 < R9 MFMA+prep 102.6 < R3 coop 144 < R8 148.7
// Levers measured null/negative: pk_fma, occupancy 2<->8 waves/SIMD, MC/KPT
// sweeps, inline-asm pipeline, coop fusion, single-pass, atomic finishers,
// MFMA (twice).  Wins: memset-dispatch removal (-3.1us), float4 reduce
// (-1.3us).  Residual: ~40us harness poison fill (85% HBM peak, its own
// roofline) + ~35us partial (pinned at ~2.5x issue floor, VALUBusy ~40%
// across 7 structural variants) + ~5us reduce + ~6us dispatch overhead.
#define BB 8
#define NN 4096
#define MC 256                    // reference points staged per chunk
#define NCHUNK (NN / MC)          // 16
#define KPT 4                     // query points per thread -> 1024 blocks
#define TPB 256
#define PTS_PER_BLOCK (TPB * KPT) // 1024
#define NPTS (2 * BB * NN)        // 65536 (both directions)

// ws layout: partial[c][zb][p]  c in [0,16), zb in [0,16), p in [0,4096) -> 4 MB

__global__ __launch_bounds__(TPB) void chamfer_partial(
    const float* __restrict__ X, const float* __restrict__ Y,
    float* __restrict__ partial, float* __restrict__ out) {
  __shared__ float4 ly[MC];       // (-2*y0, -2*y1, -2*y2, |y|^2)
  const int tid = threadIdx.x;
  const int zb  = blockIdx.z;     // (dir<<3) | b
  const int b   = zb & (BB - 1);
  const int dir = zb >> 3;
  const float* pts  = dir ? (Y + b * NN * 3) : (X + b * NN * 3);
  const float* refs = dir ? (X + b * NN * 3) : (Y + b * NN * 3);
  const int c = blockIdx.y;

  // Replaces the 4-byte hipMemsetAsync dispatch (worth -3.1us, R0->R1).
  // Safe: chamfer_reduce only touches out after this kernel completes.
  if (tid == 0 && blockIdx.x == 0 && blockIdx.y == 0 && blockIdx.z == 0)
    *out = 0.0f;

  {
    const int j = c * MC + tid;   // MC == TPB: one staging iteration
    const float a0 = refs[j * 3 + 0];
    const float a1 = refs[j * 3 + 1];
    const float a2 = refs[j * 3 + 2];
    ly[tid] = make_float4(-2.0f * a0, -2.0f * a1, -2.0f * a2,
                          a0 * a0 + a1 * a1 + a2 * a2);
  }
  __syncthreads();

  float px[KPT], py[KPT], pz[KPT], m[KPT];
  const int p0 = blockIdx.x * PTS_PER_BLOCK + tid;
#pragma unroll
  for (int k = 0; k < KPT; k++) {
    const int p = p0 + k * TPB;
    px[k] = pts[p * 3 + 0];
    py[k] = pts[p * 3 + 1];
    pz[k] = pts[p * 3 + 2];
    m[k] = 1e30f;
  }

  // min over chunk of (|y|^2 - 2 x.y); |x|^2 added after the loop.
#define CHAMFER_BODY(w0, w1, w2, w3)                                           \
  _Pragma("unroll") for (int k = 0; k < KPT; k++) {                            \
    const float s0 =                                                           \
        fmaf(px[k], w0.x, fmaf(py[k], w0.y, fmaf(pz[k], w0.z, w0.w)));         \
    const float s1 =                                                           \
        fmaf(px[k], w1.x, fmaf(py[k], w1.y, fmaf(pz[k], w1.z, w1.w)));         \
    const float s2 =                                                           \
        fmaf(px[k], w2.x, fmaf(py[k], w2.y, fmaf(pz[k], w2.z, w2.w)));         \
    const float s3 =                                                           \
        fmaf(px[k], w3.x, fmaf(py[k], w3.y, fmaf(pz[k], w3.z, w3.w)));         \
    m[k] = fminf(m[k], fminf(fminf(s0, s1), fminf(s2, s3)));                   \
  }

  float4 w0 = ly[0], w1 = ly[1], w2 = ly[2], w3 = ly[3];
#pragma unroll 2
  for (int j = 0; j < MC - 4; j += 4) {
    const float4 n0 = ly[j + 4];
    const float4 n1 = ly[j + 5];
    const float4 n2 = ly[j + 6];
    const float4 n3 = ly[j + 7];
    CHAMFER_BODY(w0, w1, w2, w3)
    w0 = n0; w1 = n1; w2 = n2; w3 = n3;
  }
  CHAMFER_BODY(w0, w1, w2, w3)
#undef CHAMFER_BODY

#pragma unroll
  for (int k = 0; k < KPT; k++) {
    const int p = p0 + k * TPB;
    const float pn = px[k] * px[k] + py[k] * py[k] + pz[k] * pz[k];
    partial[(c * (2 * BB) + zb) * NN + p] = m[k] + pn;
  }
}

// Min across chunks (float4 lanes: 16 coalesced dwordx4 loads per thread,
// all independent), block-sum, 1 atomic per block into out (zeroed by
// chamfer_partial).  Block 0 also adds L_reg.  64 blocks x 256 threads
// cover NPTS/4 float4 slots.
__global__ __launch_bounds__(256) void chamfer_reduce(
    const float4* __restrict__ partial4,
    const float* __restrict__ R, const float* __restrict__ S,
    const float* __restrict__ t, const float* __restrict__ Rgt,
    const float* __restrict__ Sgt, const float* __restrict__ tgt,
    float* __restrict__ out) {
  const int tid = threadIdx.x;
  const int q4 = blockIdx.x * 256 + tid;  // 64 blocks cover NPTS/4 = 16384
  float4 mn = make_float4(1e30f, 1e30f, 1e30f, 1e30f);
#pragma unroll
  for (int c = 0; c < NCHUNK; c++) {
    const float4 v = partial4[c * (NPTS / 4) + q4];
    mn.x = fminf(mn.x, v.x);
    mn.y = fminf(mn.y, v.y);
    mn.z = fminf(mn.z, v.z);
    mn.w = fminf(mn.w, v.w);
  }
  float s = (mn.x + mn.y) + (mn.z + mn.w);
  for (int o = 32; o > 0; o >>= 1) s += __shfl_down(s, o);
  __shared__ float wsum[4];
  if ((tid & 63) == 0) wsum[tid >> 6] = s;
  __syncthreads();
  if (tid == 0) {
    const float bs = wsum[0] + wsum[1] + wsum[2] + wsum[3];
    atomicAdd(out, bs * (1.0f / (float)(BB * NN)));
  }

  if (blockIdx.x == 0) {
    float v = 0.0f;
    if (tid < 72) {                       // R @ R_gt^T - I, squared
      const int b = tid / 9, ik = tid % 9, i = ik / 3, k = ik % 3;
      const float* Rb = R + b * 9;
      const float* Gb = Rgt + b * 9;
      float d = Rb[i * 3 + 0] * Gb[k * 3 + 0] +
                Rb[i * 3 + 1] * Gb[k * 3 + 1] +
                Rb[i * 3 + 2] * Gb[k * 3 + 2];
      d -= (i == k) ? 1.0f : 0.0f;
      v = d * d;
    } else if (tid < 96) {                // (S - S_gt)^2
      const int i = tid - 72;
      const float d = S[i] - Sgt[i];
      v = d * d;
    } else if (tid < 120) {               // (t - t_gt)^2
      const int i = tid - 96;
      const float d = t[i] - tgt[i];
      v = d * d;
    }
    for (int o = 32; o > 0; o >>= 1) v += __shfl_down(v, o);
    __shared__ float rsum[4];
    if ((tid & 63) == 0) rsum[tid >> 6] = v;
    __syncthreads();
    if (tid == 0) atomicAdd(out, rsum[0] + rsum[1] + rsum[2] + rsum[3]);
  }
}

extern "C" void kernel_launch(void* const* d_in, const int* in_sizes, int n_in,
                              void* d_out, int out_size, void* d_ws, size_t ws_size,
                              hipStream_t stream) {
  const float* X   = (const float*)d_in[0];
  const float* Y   = (const float*)d_in[1];
  const float* R   = (const float*)d_in[2];
  const float* S   = (const float*)d_in[3];
  const float* t   = (const float*)d_in[4];
  const float* Rgt = (const float*)d_in[5];
  const float* Sgt = (const float*)d_in[6];
  const float* tgt = (const float*)d_in[7];

  float* partial = (float*)d_ws;
  float* out     = (float*)d_out;

  dim3 gA(NN / PTS_PER_BLOCK, NCHUNK, 2 * BB);   // (4, 16, 16) = 1024 blocks
  chamfer_partial<<<gA, TPB, 0, stream>>>(X, Y, partial, out);

  chamfer_reduce<<<NPTS / 4 / 256, 256, 0, stream>>>(
      (const float4*)partial, R, S, t, Rgt, Sgt, tgt, out);
}